// Round 2
// baseline (392.672 us; speedup 1.0000x reference)
//
#include <hip/hip_runtime.h>
#include <hip/hip_bf16.h>

#define Bn 32
#define Ln 2048
#define Dn 768
#define Hn 512
#define Mn (Bn*Ln)
#define EPSC 1e-5f

// ws float-offset layout (first 128 KB), then byte regions
#define OFF_S1   0        // [512] masked sum(h)
#define OFF_S2   512      // [512] masked sum(h^2)
#define OFF_CNT  2048     // [32] per-batch counts
#define OFF_PH   2304     // [32*512] pooled relu(BN(h)) sums (atomic)
#define OFF_W1T_BYTES  131072   // bf16 W1^T [512][768] = 786 KB
#define OFF_H_BYTES    1048576  // tiled bf16 h buffer, 64 MB

#define BM 128
#define BN2 256
#define BK 64
#define LDK 72     // padded LDS k-stride for A (bf16): 144 B -> ~2-way banks
#define KT_N (Dn/BK)   // 12 K-tiles

typedef __attribute__((ext_vector_type(8))) short bf16x8;
typedef __attribute__((ext_vector_type(4))) float f32x4;

static __device__ __forceinline__ unsigned short f2bf(float x) {
  __hip_bfloat16 h = __float2bfloat16(x);
  return *reinterpret_cast<unsigned short*>(&h);
}
static __device__ __forceinline__ float bf2f(unsigned short u) {
  return __uint_as_float(((unsigned int)u) << 16);
}

// blocks 0..31: per-batch valid count. block 32: zero S1,S2,PH.
__global__ __launch_bounds__(256) void pre_kernel(const int* __restrict__ mask,
                                                  float* __restrict__ ws) {
  int blk = blockIdx.x, t = threadIdx.x;
  if (blk < Bn) {
    __shared__ int red[256];
    int s = 0;
#pragma unroll
    for (int i = 0; i < 8; i++) s += mask[blk * Ln + i * 256 + t];
    red[t] = s;
    __syncthreads();
    for (int off = 128; off > 0; off >>= 1) {
      if (t < off) red[t] += red[t + off];
      __syncthreads();
    }
    if (t == 0) ws[OFF_CNT + blk] = (float)red[0];
  } else {
#pragma unroll
    for (int i = 0; i < 4; i++) ws[OFF_S1 + i * 256 + t] = 0.f;
#pragma unroll
    for (int i = 0; i < 64; i++) ws[OFF_PH + i * 256 + t] = 0.f;
  }
}

// W1 [768][512] fp32 -> W1t [512][768] bf16
__global__ __launch_bounds__(256) void transpose_w1(
    const float* __restrict__ W1, unsigned short* __restrict__ W1t) {
  __shared__ float tile[32][33];
  int kx = blockIdx.x * 32;
  int nx = blockIdx.y * 32;
  int tx = threadIdx.x & 31, ty = threadIdx.x >> 5;
#pragma unroll
  for (int i = 0; i < 32; i += 8)
    tile[ty + i][tx] = W1[(size_t)(kx + ty + i) * Hn + nx + tx];
  __syncthreads();
#pragma unroll
  for (int i = 0; i < 32; i += 8)
    W1t[(size_t)(nx + ty + i) * Dn + kx + tx] = f2bf(tile[tx][ty + i]);
}

// GEMM1 v3b: 2-phase double-buffered pipeline with counted vmcnt (T3/T4-min):
//  - B staged via global_load_lds dwordx4 into linear [256][64] LDS, XOR
//    bank-swizzle realized by pre-swizzling the per-lane GLOBAL source addr
//    (gload_lds dest must be linear); ds_read applies the same involution
//    byte ^= ((row&7)<<4) -> bank-uniform ds_read_b128.
//  - A (fp32, needs cvt) reg-staged 2 sets ahead (static-indexed rAe/rAo),
//    cvt+ds_write into padded (LDK=72) slot under the MFMA phase.
//  - ONE raw s_barrier per K-step; end-of-iter wait is vmcnt(4) (drains
//    B(t+1), keeps A(t+2) in flight) -- never vmcnt(0) mid-loop.
//  - main loop FULLY unrolled (12 compile-time iters): all guards/slots
//    fold statically; no runtime branches between barriers.
// LDS: A dbuf 36.9 KB + B dbuf 64 KB + stats 2 KB = 102 KB -> 1 block/CU.
// Epilogue + Hout layout identical to round-2 kernel (bnpool-compatible):
//   chunk = by*2+bx; w*4096 + (mt*4+nt)*256 + lane*4 + r
__global__ __launch_bounds__(512, 2) void gemm1_mfma(
    const float* __restrict__ A, const unsigned short* __restrict__ W1t,
    const float* __restrict__ b1, const int* __restrict__ mask,
    unsigned short* __restrict__ Hout,
    float* __restrict__ gsum, float* __restrict__ gsq)
{
  __shared__ __align__(16) unsigned short As3[2][BM * LDK];   // padded [m][k]
  __shared__ __align__(16) unsigned short Bs3[2][BN2 * BK];   // linear, swizzled content
  __shared__ float csum[BN2];
  __shared__ float csq[BN2];

  const int t = threadIdx.x;
  const int bx = blockIdx.x;   // N: 0..1
  const int by = blockIdx.y;   // M: 0..511
  const int bm0 = by * BM;
  const int bn0 = bx * BN2;

  const int w = t >> 6;
  const int lane = t & 63;
  const int wm0 = (w >> 2) * 64;
  const int wn0 = (w & 3) * 64;
  const int l15 = lane & 15;
  const int quad = lane >> 4;

  // A staging map: thread covers 16 consecutive floats of its row
  const int am = t >> 2;           // 0..127
  const int ak = (t & 3) * 16;     // 0/16/32/48
  const float* Ap = A + (size_t)(bm0 + am) * Dn + ak;

  f32x4 acc[4][4];
#pragma unroll
  for (int i = 0; i < 4; i++)
#pragma unroll
    for (int j = 0; j < 4; j++) acc[i][j] = (f32x4){0.f, 0.f, 0.f, 0.f};

  float4 rAe[4], rAo[4];   // 2-deep A prefetch sets (always literal-indexed)

#define WAITV(N) do { asm volatile("s_waitcnt vmcnt(" #N ")" ::: "memory"); \
                      __builtin_amdgcn_sched_barrier(0); } while (0)
#define WAITL0() do { asm volatile("s_waitcnt lgkmcnt(0)" ::: "memory"); \
                      __builtin_amdgcn_sched_barrier(0); } while (0)

  // Stage B tile KT2 into slot NS. LDS phys byte p holds logical tile byte
  // q = p ^ ((p>>7 & 7)<<4)  (involution, col bits 4-6 only). Global src is
  // per-lane; LDS dest is wave-uniform (+lane*16 added by HW).
#define STAGE_B(KT2, NS) do { \
  _Pragma("unroll") \
  for (int j = 0; j < 4; ++j) { \
    const int p = ((w * 4 + j) << 10) + (lane << 4); \
    const int q = p ^ (((p >> 7) & 7) << 4); \
    const char* gsrc = (const char*)(W1t + (size_t)(bn0 + (q >> 7)) * Dn \
                                     + (KT2) * BK) + (q & 127); \
    __builtin_amdgcn_global_load_lds( \
        (const __attribute__((address_space(1))) void*)gsrc, \
        (__attribute__((address_space(3))) void*)((char*)&Bs3[NS][0] \
                                                  + ((w * 4 + j) << 10)), \
        16, 0, 0); \
  } \
} while (0)

#define LOAD_A(KT, R) do { \
  R[0] = *(const float4*)(Ap + (KT) * BK); \
  R[1] = *(const float4*)(Ap + (KT) * BK + 4); \
  R[2] = *(const float4*)(Ap + (KT) * BK + 8); \
  R[3] = *(const float4*)(Ap + (KT) * BK + 12); \
} while (0)

#define PACK_WRITE(R, NS) do { \
  uint4 p0, p1; \
  p0.x = (unsigned)f2bf(R[0].x) | ((unsigned)f2bf(R[0].y) << 16); \
  p0.y = (unsigned)f2bf(R[0].z) | ((unsigned)f2bf(R[0].w) << 16); \
  p0.z = (unsigned)f2bf(R[1].x) | ((unsigned)f2bf(R[1].y) << 16); \
  p0.w = (unsigned)f2bf(R[1].z) | ((unsigned)f2bf(R[1].w) << 16); \
  p1.x = (unsigned)f2bf(R[2].x) | ((unsigned)f2bf(R[2].y) << 16); \
  p1.y = (unsigned)f2bf(R[2].z) | ((unsigned)f2bf(R[2].w) << 16); \
  p1.z = (unsigned)f2bf(R[3].x) | ((unsigned)f2bf(R[3].y) << 16); \
  p1.w = (unsigned)f2bf(R[3].z) | ((unsigned)f2bf(R[3].w) << 16); \
  *(uint4*)&As3[NS][am * LDK + ak] = p0; \
  *(uint4*)&As3[NS][am * LDK + ak + 8] = p1; \
} while (0)

#define MFMA_ALL(CS) do { \
  _Pragma("unroll") \
  for (int s = 0; s < 2; ++s) { \
    bf16x8 af[4], bf[4]; \
    _Pragma("unroll") \
    for (int mt = 0; mt < 4; ++mt) \
      af[mt] = *(const bf16x8*)&As3[CS][(wm0 + mt * 16 + l15) * LDK \
                                        + s * 32 + quad * 8]; \
    _Pragma("unroll") \
    for (int nt = 0; nt < 4; ++nt) { \
      const int rb = wn0 + nt * 16 + l15; \
      const int cb = (s * 64 + quad * 16) ^ ((rb & 7) << 4); \
      bf[nt] = *(const bf16x8*)((const char*)&Bs3[CS][0] + rb * 128 + cb); \
    } \
    _Pragma("unroll") \
    for (int mt = 0; mt < 4; ++mt) \
      _Pragma("unroll") \
      for (int nt = 0; nt < 4; ++nt) \
        acc[mt][nt] = __builtin_amdgcn_mfma_f32_16x16x32_bf16( \
            af[mt], bf[nt], acc[mt][nt], 0, 0, 0); \
  } \
} while (0)

  // Issue order inside an iter: B gloads FIRST, then A loads (sched_barrier
  // pins FIFO order), so end-of-iter vmcnt(4) drains B(t+1), keeps A(t+2).
#define K_ITER(KT, CS, RL, RW) do { \
  if ((KT) < KT_N - 1) STAGE_B((KT) + 1, (CS) ^ 1); \
  __builtin_amdgcn_sched_barrier(0); \
  if ((KT) < KT_N - 2) LOAD_A((KT) + 2, RL); \
  if ((KT) < KT_N - 1) PACK_WRITE(RW, (CS) ^ 1); \
  MFMA_ALL(CS); \
  if ((KT) < KT_N - 2) { WAITV(4); } else { WAITV(0); } \
  WAITL0(); \
  __builtin_amdgcn_s_barrier(); \
} while (0)

  // ---- prologue: stage tile 0, prefetch A(0),A(1); conservative drain ----
  STAGE_B(0, 0);
  __builtin_amdgcn_sched_barrier(0);
  LOAD_A(0, rAe);
  LOAD_A(1, rAo);
  WAITV(0);                 // drain B(0)+A(0)+A(1) (once; order-insensitive)
  PACK_WRITE(rAe, 0);
  WAITL0();
  __builtin_amdgcn_s_barrier();

  // ---- main loop: 12 K-steps, FULLY unrolled (compile-time KT/slots) ----
#pragma unroll
  for (int k2 = 0; k2 < KT_N / 2; ++k2) {
    K_ITER(k2 * 2,     0, rAe, rAo);
    K_ITER(k2 * 2 + 1, 1, rAo, rAe);
  }

#undef K_ITER
#undef MFMA_ALL
#undef PACK_WRITE
#undef LOAD_A
#undef STAGE_B
#undef WAITL0
#undef WAITV

  // ---- epilogue: bias, masked stats, coalesced tiled bf16 store ----
  if (t < BN2) { csum[t] = 0.f; csq[t] = 0.f; }
  __syncthreads();

  float mk[4][4];
#pragma unroll
  for (int mt = 0; mt < 4; mt++) {
    int4 mv = *(const int4*)(mask + bm0 + wm0 + mt * 16 + quad * 4);
    mk[mt][0] = (float)mv.x; mk[mt][1] = (float)mv.y;
    mk[mt][2] = (float)mv.z; mk[mt][3] = (float)mv.w;
  }

  const size_t cbase = ((size_t)(by * 2 + bx)) * 32768 + (size_t)w * 4096;
#pragma unroll
  for (int nt = 0; nt < 4; nt++) {
    const int nl = wn0 + nt * 16 + l15;
    const float bias = b1[bn0 + nl];
    float ps = 0.f, pq = 0.f;
#pragma unroll
    for (int mt = 0; mt < 4; mt++) {
      ushort4 st;
      float v0 = acc[mt][nt][0] + bias;
      float v1 = acc[mt][nt][1] + bias;
      float v2 = acc[mt][nt][2] + bias;
      float v3 = acc[mt][nt][3] + bias;
      ps += v0 * mk[mt][0] + v1 * mk[mt][1] + v2 * mk[mt][2] + v3 * mk[mt][3];
      pq += v0 * v0 * mk[mt][0] + v1 * v1 * mk[mt][1] +
            v2 * v2 * mk[mt][2] + v3 * v3 * mk[mt][3];
      st.x = f2bf(v0); st.y = f2bf(v1); st.z = f2bf(v2); st.w = f2bf(v3);
      *(ushort4*)&Hout[cbase + (size_t)(mt * 4 + nt) * 256 + lane * 4] = st;
    }
    atomicAdd(&csum[nl], ps);
    atomicAdd(&csq[nl], pq);
  }

  __syncthreads();
  if (t < BN2) {
    atomicAdd(&gsum[bn0 + t], csum[t]);
    atomicAdd(&gsq[bn0 + t], csq[t]);
  }
}

// BN(finalize fused) + ReLU + masked pool over the tiled Hout layout.
__global__ __launch_bounds__(256) void bnpool_kernel(
    const unsigned short* __restrict__ Hbuf, const int* __restrict__ mask,
    const float* __restrict__ ws, const float* __restrict__ gamma,
    const float* __restrict__ beta, float* __restrict__ PH)
{
  __shared__ float mkf[BM];
  __shared__ float redc[32];
  const int t = threadIdx.x;
  const int chunk = blockIdx.x;        // 0..1023
  const int by = chunk >> 1, bx = chunk & 1;
  const int b = chunk >> 5;            // 32 chunks per batch
  if (t < 32) redc[t] = ws[OFF_CNT + t];
  if (t < BM) mkf[t] = (float)mask[by * BM + t];
  __syncthreads();

  float nv = 0.f;
#pragma unroll
  for (int i = 0; i < 32; i++) nv += redc[i];
  nv = fmaxf(nv, 1.f);
  const float inv = 1.f / nv;
  const int c = bx * BN2 + t;
  const float m = ws[OFF_S1 + c] * inv;
  const float var = ws[OFF_S2 + c] * inv - m * m;
  const float istd = rsqrtf(fmaxf(var, 0.f) + EPSC);
  const float scv = istd * gamma[c];
  const float shv = beta[c] - m * scv;

  const int w3 = t >> 6, nt = (t >> 4) & 3, l15 = t & 15;
  float acc = 0.f;
#pragma unroll
  for (int h = 0; h < 2; h++) {
    const int w = w3 + h * 4;          // same wn0 group, wm half h
    const int wm0 = h * 64;
    const unsigned short* base =
        Hbuf + (size_t)chunk * 32768 + (size_t)w * 4096 + nt * 256 + l15 * 4;
#pragma unroll
    for (int mt = 0; mt < 4; mt++)
#pragma unroll
      for (int q = 0; q < 4; q++) {
        ushort4 hv = *(const ushort4*)(base + mt * 1024 + q * 64);
        const float* mv = &mkf[wm0 + mt * 16 + q * 4];
        acc += fmaxf(fmaf(bf2f(hv.x), scv, shv), 0.f) * mv[0]
             + fmaxf(fmaf(bf2f(hv.y), scv, shv), 0.f) * mv[1]
             + fmaxf(fmaf(bf2f(hv.z), scv, shv), 0.f) * mv[2]
             + fmaxf(fmaf(bf2f(hv.w), scv, shv), 0.f) * mv[3];
      }
  }
  atomicAdd(&PH[b * Hn + c], acc);
}

// out[b][c] = (PH[b]/max(cnt,1)) @ W2[:,c] + b2[c]*(cnt/max(cnt,1))
__global__ __launch_bounds__(128) void final_kernel(
    const float* __restrict__ pooledh, const float* __restrict__ cnt,
    const float* __restrict__ W2, const float* __restrict__ b2,
    float* __restrict__ out)
{
  __shared__ float pr[Hn];
  int b = blockIdx.x >> 2;
  int cc = blockIdx.x & 3;
  int t = threadIdx.x;
  float nb = cnt[b];
  float inv = 1.f / fmaxf(nb, 1.f);
#pragma unroll
  for (int i = 0; i < 4; i++)
    pr[t + i * 128] = pooledh[b * Hn + t + i * 128] * inv;
  __syncthreads();
  int c = cc * 128 + t;
  float a0 = 0.f, a1 = 0.f, a2 = 0.f, a3 = 0.f;
  for (int i = 0; i < Hn; i += 4) {
    a0 = fmaf(pr[i],     W2[(size_t)i * Hn + c],       a0);
    a1 = fmaf(pr[i + 1], W2[(size_t)(i + 1) * Hn + c], a1);
    a2 = fmaf(pr[i + 2], W2[(size_t)(i + 2) * Hn + c], a2);
    a3 = fmaf(pr[i + 3], W2[(size_t)(i + 3) * Hn + c], a3);
  }
  out[b * Hn + c] = (a0 + a1) + (a2 + a3) + b2[c] * (nb * inv);
}

extern "C" void kernel_launch(void* const* d_in, const int* in_sizes, int n_in,
                              void* d_out, int out_size, void* d_ws, size_t ws_size,
                              hipStream_t stream) {
  const float* hidden = (const float*)d_in[0];
  const int*   mask   = (const int*)d_in[1];
  const float* W1     = (const float*)d_in[2];
  const float* b1     = (const float*)d_in[3];
  const float* gamma  = (const float*)d_in[4];
  const float* beta   = (const float*)d_in[5];
  const float* W2     = (const float*)d_in[6];
  const float* b2     = (const float*)d_in[7];
  float* out = (float*)d_out;
  float* ws  = (float*)d_ws;
  unsigned short* W1t  = (unsigned short*)((char*)d_ws + OFF_W1T_BYTES);
  unsigned short* Hbuf = (unsigned short*)((char*)d_ws + OFF_H_BYTES);

  pre_kernel<<<Bn + 1, 256, 0, stream>>>(mask, ws);
  transpose_w1<<<dim3(Dn / 32, Hn / 32), 256, 0, stream>>>(W1, W1t);
  gemm1_mfma<<<dim3(Hn / BN2, Mn / BM), 512, 0, stream>>>(
      hidden, W1t, b1, mask, Hbuf, ws + OFF_S1, ws + OFF_S2);
  bnpool_kernel<<<(Mn / BM) * (Hn / BN2), 256, 0, stream>>>(
      Hbuf, mask, ws, gamma, beta, ws + OFF_PH);
  final_kernel<<<Bn * 4, 128, 0, stream>>>(ws + OFF_PH, ws + OFF_CNT, W2, b2, out);
}